// Round 1
// baseline (2738.931 us; speedup 1.0000x reference)
//
#include <hip/hip_runtime.h>
#include <hip/hip_bf16.h>

#define N_NODES 100000
#define N_EDGES 1600000
#define F_IN 256
#define F_OUT 128

typedef __attribute__((ext_vector_type(8))) short short8;
typedef __attribute__((ext_vector_type(4))) float f32x4;

static __device__ __forceinline__ short bf16b(float f) {
    __hip_bfloat16 h = __float2bfloat16(f);
    return *reinterpret_cast<short*>(&h);
}

// Kernel 1: pack W [256][128] f32 -> W_sw bf16 laid out [ks(8)][kk(4)][col(128)][e(8)]
// so a B-fragment (16x16x32 MFMA) is one contiguous 16B read per lane.
__global__ void wprep_kernel(const float* __restrict__ W, short* __restrict__ Wsw) {
    int idx = blockIdx.x * 256 + threadIdx.x;   // 0..32767
    int e  = idx & 7;
    int col = (idx >> 3) & 127;
    int kk = (idx >> 10) & 3;
    int ks = idx >> 12;
    int k = ks * 32 + kk * 8 + e;
    Wsw[idx] = bf16b(W[k * 128 + col]);
}

// Kernel 2: pre_sup = x @ W via v_mfma_f32_16x16x32_bf16.
// 256 threads = 4 waves; each wave owns 16 rows x 128 cols; K=256 in 8 steps.
// No LDS: A-fragments straight from global x (row read exactly once),
// B-fragments from the pre-swizzled Wsw (L2-resident, 64KB).
__global__ void gemm_kernel(const float* __restrict__ x, const short* __restrict__ Wsw,
                            float* __restrict__ pre) {
    const int lane = threadIdx.x & 63;
    const int wave = threadIdx.x >> 6;
    const int m0 = blockIdx.x * 64 + wave * 16;
    const int l15 = lane & 15;
    const int kk = lane >> 4;

    int r = m0 + l15;
    if (r > N_NODES - 1) r = N_NODES - 1;   // clamp for load safety; stores guarded
    const float* xr = x + (long)r * F_IN;

    f32x4 acc[8];
#pragma unroll
    for (int i = 0; i < 8; ++i) acc[i] = (f32x4){0.f, 0.f, 0.f, 0.f};

#pragma unroll
    for (int ks = 0; ks < 8; ++ks) {
        float4 xa = *reinterpret_cast<const float4*>(xr + ks * 32 + kk * 8);
        float4 xb = *reinterpret_cast<const float4*>(xr + ks * 32 + kk * 8 + 4);
        short8 a;
        a[0] = bf16b(xa.x); a[1] = bf16b(xa.y); a[2] = bf16b(xa.z); a[3] = bf16b(xa.w);
        a[4] = bf16b(xb.x); a[5] = bf16b(xb.y); a[6] = bf16b(xb.z); a[7] = bf16b(xb.w);
        const short8* wv = reinterpret_cast<const short8*>(Wsw) + ((ks * 4 + kk) * 128 + l15);
#pragma unroll
        for (int nf = 0; nf < 8; ++nf) {
            short8 b = wv[nf * 16];
            acc[nf] = __builtin_amdgcn_mfma_f32_16x16x32_bf16(a, b, acc[nf], 0, 0, 0);
        }
    }

    // C/D layout (HW-verified): col = lane&15, row = (lane>>4)*4 + reg
    const int rbase = m0 + (lane >> 4) * 4;
#pragma unroll
    for (int nf = 0; nf < 8; ++nf) {
        int cc = nf * 16 + l15;
#pragma unroll
        for (int reg = 0; reg < 4; ++reg) {
            int rr = rbase + reg;
            if (rr < N_NODES) pre[(long)rr * F_OUT + cc] = acc[nf][reg];
        }
    }
}

// Kernel 3: edge-parallel SpMM scatter: out[row[e]] += vals[e] * pre_sup[col[e]]
// 32 threads per edge, float4 gather (512B contiguous per edge), HW f32 atomics.
__global__ void spmm_kernel(const float* __restrict__ pre, const int* __restrict__ row,
                            const int* __restrict__ col, const float* __restrict__ vals,
                            float* __restrict__ out) {
    int t = blockIdx.x * 256 + threadIdx.x;
    int e = t >> 5;
    int q = t & 31;
    int r = row[e];
    int c = col[e];
    float v = vals[e];
    float4 m = reinterpret_cast<const float4*>(pre + (long)c * F_OUT)[q];
    float* dst = out + (long)r * F_OUT + q * 4;
    unsafeAtomicAdd(dst + 0, v * m.x);
    unsafeAtomicAdd(dst + 1, v * m.y);
    unsafeAtomicAdd(dst + 2, v * m.z);
    unsafeAtomicAdd(dst + 3, v * m.w);
}

// Kernel 4: out = relu(out + b), in place, float4.
__global__ void bias_relu_kernel(float* __restrict__ out, const float* __restrict__ b) {
    int idx = blockIdx.x * 256 + threadIdx.x;   // quad index
    float4* p = reinterpret_cast<float4*>(out) + idx;
    float4 v = *p;
    int j0 = (idx & 31) * 4;                    // 32 quads per 128-col row
    v.x = fmaxf(v.x + b[j0 + 0], 0.f);
    v.y = fmaxf(v.y + b[j0 + 1], 0.f);
    v.z = fmaxf(v.z + b[j0 + 2], 0.f);
    v.w = fmaxf(v.w + b[j0 + 3], 0.f);
    *p = v;
}

extern "C" void kernel_launch(void* const* d_in, const int* in_sizes, int n_in,
                              void* d_out, int out_size, void* d_ws, size_t ws_size,
                              hipStream_t stream) {
    const float* x    = (const float*)d_in[0];
    const float* W    = (const float*)d_in[1];
    const float* b    = (const float*)d_in[2];
    const float* vals = (const float*)d_in[3];
    const int*   row  = (const int*)d_in[4];
    const int*   col  = (const int*)d_in[5];
    float* out = (float*)d_out;

    float* pre = (float*)d_ws;                                        // 51.2 MB f32
    short* Wsw = (short*)((char*)d_ws + (size_t)N_NODES * F_OUT * 4); // 64 KB bf16

    // out accumulates the scatter; zero it each call (harness poisons, never re-zeros).
    hipMemsetAsync(d_out, 0, (size_t)N_NODES * F_OUT * sizeof(float), stream);

    wprep_kernel<<<128, 256, 0, stream>>>(W, Wsw);
    gemm_kernel<<<(N_NODES + 63) / 64, 256, 0, stream>>>(x, Wsw, pre);
    spmm_kernel<<<(N_EDGES * 32) / 256, 256, 0, stream>>>(pre, row, col, vals, out);
    bias_relu_kernel<<<(N_NODES * F_OUT / 4) / 256, 256, 0, stream>>>(out, b);
}

// Round 2
// 313.283 us; speedup vs baseline: 8.7427x; 8.7427x over previous
//
#include <hip/hip_runtime.h>
#include <hip/hip_bf16.h>

#define N_NODES 100000
#define N_EDGES 1600000
#define F_IN 256
#define F_OUT 128
#define SCAN_BLOCKS ((N_NODES + 255) / 256)   // 391

typedef __attribute__((ext_vector_type(8))) short short8;
typedef __attribute__((ext_vector_type(4))) float f32x4;

static __device__ __forceinline__ unsigned short bf16b(float f) {
    __hip_bfloat16 h = __float2bfloat16(f);
    return *reinterpret_cast<unsigned short*>(&h);
}

// ---------- Kernel 1: pack W [256][128] f32 -> bf16 [ks(8)][kk(4)][col(128)][e(8)] ----------
__global__ void wprep_kernel(const float* __restrict__ W, unsigned short* __restrict__ Wsw) {
    int idx = blockIdx.x * 256 + threadIdx.x;   // 0..32767
    int e  = idx & 7;
    int col = (idx >> 3) & 127;
    int kk = (idx >> 10) & 3;
    int ks = idx >> 12;
    int k = ks * 32 + kk * 8 + e;
    Wsw[idx] = bf16b(W[k * 128 + col]);
}

// ---------- Kernel 2: pre = bf16(x @ W) via v_mfma_f32_16x16x32_bf16, no LDS ----------
__global__ void gemm_kernel(const float* __restrict__ x, const unsigned short* __restrict__ Wsw,
                            unsigned short* __restrict__ preb) {
    const int lane = threadIdx.x & 63;
    const int wave = threadIdx.x >> 6;
    const int m0 = blockIdx.x * 64 + wave * 16;
    const int l15 = lane & 15;
    const int kk = lane >> 4;

    int r = m0 + l15;
    if (r > N_NODES - 1) r = N_NODES - 1;   // clamp for load safety; stores guarded
    const float* xr = x + (long)r * F_IN;

    f32x4 acc[8];
#pragma unroll
    for (int i = 0; i < 8; ++i) acc[i] = (f32x4){0.f, 0.f, 0.f, 0.f};

#pragma unroll
    for (int ks = 0; ks < 8; ++ks) {
        float4 xa = *reinterpret_cast<const float4*>(xr + ks * 32 + kk * 8);
        float4 xb = *reinterpret_cast<const float4*>(xr + ks * 32 + kk * 8 + 4);
        short8 a;
        a[0] = (short)bf16b(xa.x); a[1] = (short)bf16b(xa.y); a[2] = (short)bf16b(xa.z); a[3] = (short)bf16b(xa.w);
        a[4] = (short)bf16b(xb.x); a[5] = (short)bf16b(xb.y); a[6] = (short)bf16b(xb.z); a[7] = (short)bf16b(xb.w);
        const short8* wv = reinterpret_cast<const short8*>(Wsw) + ((ks * 4 + kk) * 128 + l15);
#pragma unroll
        for (int nf = 0; nf < 8; ++nf) {
            short8 b = wv[nf * 16];
            acc[nf] = __builtin_amdgcn_mfma_f32_16x16x32_bf16(a, b, acc[nf], 0, 0, 0);
        }
    }

    // C/D layout: col = lane&15, row = (lane>>4)*4 + reg
    const int rbase = m0 + (lane >> 4) * 4;
#pragma unroll
    for (int nf = 0; nf < 8; ++nf) {
        int cc = nf * 16 + l15;
#pragma unroll
        for (int reg = 0; reg < 4; ++reg) {
            int rr = rbase + reg;
            if (rr < N_NODES) preb[(long)rr * F_OUT + cc] = bf16b(acc[nf][reg]);
        }
    }
}

// ---------- CSR build ----------
__global__ void hist_kernel(const int* __restrict__ row, int* __restrict__ deg) {
    int e = blockIdx.x * 256 + threadIdx.x;
    if (e < N_EDGES) atomicAdd(&deg[row[e]], 1);
}

// Per-block inclusive scan of deg -> within-block exclusive into row_start, block totals into bsums.
__global__ void scan_block_kernel(const int* __restrict__ deg, int* __restrict__ row_start,
                                  int* __restrict__ bsums) {
    __shared__ int tmp[256];
    int t = threadIdx.x;
    int i = blockIdx.x * 256 + t;
    int d = (i < N_NODES) ? deg[i] : 0;
    tmp[t] = d;
    __syncthreads();
#pragma unroll
    for (int o = 1; o < 256; o <<= 1) {
        int v = (t >= o) ? tmp[t - o] : 0;
        __syncthreads();
        tmp[t] += v;
        __syncthreads();
    }
    if (i < N_NODES) row_start[i] = tmp[t] - d;      // exclusive within block
    if (t == 255) bsums[blockIdx.x] = tmp[255];      // block total
}

// Single-block exclusive scan of the 391 block sums (padded to 512).
__global__ void scan_bsums_kernel(int* __restrict__ bsums) {
    __shared__ int tmp[512];
    int t = threadIdx.x;
    int v = (t < SCAN_BLOCKS) ? bsums[t] : 0;
    tmp[t] = v;
    __syncthreads();
#pragma unroll
    for (int o = 1; o < 512; o <<= 1) {
        int u = (t >= o) ? tmp[t - o] : 0;
        __syncthreads();
        tmp[t] += u;
        __syncthreads();
    }
    bsums[t] = tmp[t] - v;                           // exclusive
}

// Add block offsets; write final row_start and a working copy into cursor.
__global__ void scan_add_kernel(int* __restrict__ row_start, const int* __restrict__ bsums,
                                int* __restrict__ cursor) {
    int i = blockIdx.x * 256 + threadIdx.x;
    if (i < N_NODES) {
        int v = row_start[i] + bsums[blockIdx.x];
        row_start[i] = v;
        cursor[i] = v;
        if (i == N_NODES - 1) row_start[N_NODES] = N_EDGES;
    }
}

// Scatter edges into CSR slots: edges[pos] = {col, bits(val)}.
__global__ void scatter_kernel(const int* __restrict__ row, const int* __restrict__ col,
                               const float* __restrict__ vals, int* __restrict__ cursor,
                               uint2* __restrict__ edges) {
    int e = blockIdx.x * 256 + threadIdx.x;
    if (e < N_EDGES) {
        int pos = atomicAdd(&cursor[row[e]], 1);
        edges[pos] = make_uint2((unsigned)col[e], __float_as_uint(vals[e]));
    }
}

// ---------- Kernel 3: CSR SpMM, one wave per row, fused bias+ReLU, write-once ----------
__global__ __launch_bounds__(256) void spmm_csr_kernel(
    const unsigned short* __restrict__ preb, const int* __restrict__ row_start,
    const uint2* __restrict__ edges, const float* __restrict__ bias,
    float* __restrict__ out) {
    const int lane = threadIdx.x & 63;
    const int r = blockIdx.x * 4 + (threadIdx.x >> 6);
    const int s = row_start[r];
    const int t = row_start[r + 1];
    float a0 = 0.f, a1 = 0.f;
    int e = s;
    // 4x unrolled gather: independent loads pipeline under the FMA chain.
    for (; e + 4 <= t; e += 4) {
        uint2 cv0 = edges[e + 0];
        uint2 cv1 = edges[e + 1];
        uint2 cv2 = edges[e + 2];
        uint2 cv3 = edges[e + 3];
        unsigned g0 = *reinterpret_cast<const unsigned*>(preb + (size_t)cv0.x * F_OUT + lane * 2);
        unsigned g1 = *reinterpret_cast<const unsigned*>(preb + (size_t)cv1.x * F_OUT + lane * 2);
        unsigned g2 = *reinterpret_cast<const unsigned*>(preb + (size_t)cv2.x * F_OUT + lane * 2);
        unsigned g3 = *reinterpret_cast<const unsigned*>(preb + (size_t)cv3.x * F_OUT + lane * 2);
        float v0 = __uint_as_float(cv0.y), v1 = __uint_as_float(cv1.y);
        float v2 = __uint_as_float(cv2.y), v3 = __uint_as_float(cv3.y);
        a0 += v0 * __uint_as_float(g0 << 16);
        a1 += v0 * __uint_as_float(g0 & 0xFFFF0000u);
        a0 += v1 * __uint_as_float(g1 << 16);
        a1 += v1 * __uint_as_float(g1 & 0xFFFF0000u);
        a0 += v2 * __uint_as_float(g2 << 16);
        a1 += v2 * __uint_as_float(g2 & 0xFFFF0000u);
        a0 += v3 * __uint_as_float(g3 << 16);
        a1 += v3 * __uint_as_float(g3 & 0xFFFF0000u);
    }
    for (; e < t; ++e) {
        uint2 cv = edges[e];
        float v = __uint_as_float(cv.y);
        unsigned g = *reinterpret_cast<const unsigned*>(preb + (size_t)cv.x * F_OUT + lane * 2);
        a0 += v * __uint_as_float(g << 16);
        a1 += v * __uint_as_float(g & 0xFFFF0000u);
    }
    float2 bb = *reinterpret_cast<const float2*>(bias + lane * 2);
    float2 o;
    o.x = fmaxf(a0 + bb.x, 0.f);
    o.y = fmaxf(a1 + bb.y, 0.f);
    *reinterpret_cast<float2*>(out + (size_t)r * F_OUT + lane * 2) = o;
}

extern "C" void kernel_launch(void* const* d_in, const int* in_sizes, int n_in,
                              void* d_out, int out_size, void* d_ws, size_t ws_size,
                              hipStream_t stream) {
    const float* x    = (const float*)d_in[0];
    const float* W    = (const float*)d_in[1];
    const float* b    = (const float*)d_in[2];
    const float* vals = (const float*)d_in[3];
    const int*   row  = (const int*)d_in[4];
    const int*   col  = (const int*)d_in[5];
    float* out = (float*)d_out;

    // Workspace layout (16B-aligned offsets), total ~39.3 MB:
    char* ws = (char*)d_ws;
    unsigned short* preb  = (unsigned short*)(ws);                    // 25,600,000 B
    unsigned short* Wsw   = (unsigned short*)(ws + 25600000);         //     65,536 B
    int*            row_start = (int*)(ws + 25665536);                //    400,016 B (100001 ints)
    int*            cursor    = (int*)(ws + 26065552);                //    400,000 B (deg, then cursors)
    int*            bsums     = (int*)(ws + 26465552);                //      4,096 B
    uint2*          edges     = (uint2*)(ws + 26469648);              // 12,800,000 B

    // deg accumulates in `cursor` first; zero it each call.
    hipMemsetAsync(cursor, 0, N_NODES * sizeof(int), stream);

    wprep_kernel<<<128, 256, 0, stream>>>(W, Wsw);
    gemm_kernel<<<(N_NODES + 63) / 64, 256, 0, stream>>>(x, Wsw, preb);

    hist_kernel<<<(N_EDGES + 255) / 256, 256, 0, stream>>>(row, cursor);
    scan_block_kernel<<<SCAN_BLOCKS, 256, 0, stream>>>(cursor, row_start, bsums);
    scan_bsums_kernel<<<1, 512, 0, stream>>>(bsums);
    scan_add_kernel<<<SCAN_BLOCKS, 256, 0, stream>>>(row_start, bsums, cursor);
    scatter_kernel<<<(N_EDGES + 255) / 256, 256, 0, stream>>>(row, col, vals, cursor, edges);

    spmm_csr_kernel<<<N_NODES / 4, 256, 0, stream>>>(preb, row_start, edges, b, out);
}

// Round 3
// 262.183 us; speedup vs baseline: 10.4466x; 1.1949x over previous
//
#include <hip/hip_runtime.h>
#include <hip/hip_bf16.h>

#define N_NODES 100000
#define N_EDGES 1600000
#define F_IN 256
#define F_OUT 128
#define SCAN_BLOCKS ((N_NODES + 255) / 256)   // 391

// XCD-binned scatter geometry: 8 bins x 12500 rows; 250 chunks x 6400 edges.
#define N_BINS 8
#define BIN_ROWS 12500
#define SC_CHUNKS 250
#define SC_CHUNK_EDGES 6400

typedef __attribute__((ext_vector_type(8))) short short8;
typedef __attribute__((ext_vector_type(4))) float f32x4;

static __device__ __forceinline__ unsigned short bf16b(float f) {
    __hip_bfloat16 h = __float2bfloat16(f);
    return *reinterpret_cast<unsigned short*>(&h);
}

// ---------- Kernel 1: pack W [256][128] f32 -> bf16 [ks(8)][kk(4)][col(128)][e(8)] ----------
__global__ void wprep_kernel(const float* __restrict__ W, unsigned short* __restrict__ Wsw) {
    int idx = blockIdx.x * 256 + threadIdx.x;   // 0..32767
    int e  = idx & 7;
    int col = (idx >> 3) & 127;
    int kk = (idx >> 10) & 3;
    int ks = idx >> 12;
    int k = ks * 32 + kk * 8 + e;
    Wsw[idx] = bf16b(W[k * 128 + col]);
}

// ---------- Kernel 2: pre = bf16(x @ W) via v_mfma_f32_16x16x32_bf16, no LDS ----------
__global__ void gemm_kernel(const float* __restrict__ x, const unsigned short* __restrict__ Wsw,
                            unsigned short* __restrict__ preb) {
    const int lane = threadIdx.x & 63;
    const int wave = threadIdx.x >> 6;
    const int m0 = blockIdx.x * 64 + wave * 16;
    const int l15 = lane & 15;
    const int kk = lane >> 4;

    int r = m0 + l15;
    if (r > N_NODES - 1) r = N_NODES - 1;   // clamp for load safety; stores guarded
    const float* xr = x + (long)r * F_IN;

    f32x4 acc[8];
#pragma unroll
    for (int i = 0; i < 8; ++i) acc[i] = (f32x4){0.f, 0.f, 0.f, 0.f};

#pragma unroll
    for (int ks = 0; ks < 8; ++ks) {
        float4 xa = *reinterpret_cast<const float4*>(xr + ks * 32 + kk * 8);
        float4 xb = *reinterpret_cast<const float4*>(xr + ks * 32 + kk * 8 + 4);
        short8 a;
        a[0] = (short)bf16b(xa.x); a[1] = (short)bf16b(xa.y); a[2] = (short)bf16b(xa.z); a[3] = (short)bf16b(xa.w);
        a[4] = (short)bf16b(xb.x); a[5] = (short)bf16b(xb.y); a[6] = (short)bf16b(xb.z); a[7] = (short)bf16b(xb.w);
        const short8* wv = reinterpret_cast<const short8*>(Wsw) + ((ks * 4 + kk) * 128 + l15);
#pragma unroll
        for (int nf = 0; nf < 8; ++nf) {
            short8 b = wv[nf * 16];
            acc[nf] = __builtin_amdgcn_mfma_f32_16x16x32_bf16(a, b, acc[nf], 0, 0, 0);
        }
    }

    // C/D layout: col = lane&15, row = (lane>>4)*4 + reg
    const int rbase = m0 + (lane >> 4) * 4;
#pragma unroll
    for (int nf = 0; nf < 8; ++nf) {
        int cc = nf * 16 + l15;
#pragma unroll
        for (int reg = 0; reg < 4; ++reg) {
            int rr = rbase + reg;
            if (rr < N_NODES) preb[(long)rr * F_OUT + cc] = bf16b(acc[nf][reg]);
        }
    }
}

// ---------- CSR build ----------
__global__ void hist_kernel(const int* __restrict__ row, int* __restrict__ deg) {
    int e = blockIdx.x * 256 + threadIdx.x;
    if (e < N_EDGES) atomicAdd(&deg[row[e]], 1);
}

// Per-block inclusive scan of deg -> within-block exclusive into row_start, block totals into bsums.
__global__ void scan_block_kernel(const int* __restrict__ deg, int* __restrict__ row_start,
                                  int* __restrict__ bsums) {
    __shared__ int tmp[256];
    int t = threadIdx.x;
    int i = blockIdx.x * 256 + t;
    int d = (i < N_NODES) ? deg[i] : 0;
    tmp[t] = d;
    __syncthreads();
#pragma unroll
    for (int o = 1; o < 256; o <<= 1) {
        int v = (t >= o) ? tmp[t - o] : 0;
        __syncthreads();
        tmp[t] += v;
        __syncthreads();
    }
    if (i < N_NODES) row_start[i] = tmp[t] - d;      // exclusive within block
    if (t == 255) bsums[blockIdx.x] = tmp[255];      // block total
}

// Single-block exclusive scan of the 391 block sums (padded to 512).
__global__ void scan_bsums_kernel(int* __restrict__ bsums) {
    __shared__ int tmp[512];
    int t = threadIdx.x;
    int v = (t < SCAN_BLOCKS) ? bsums[t] : 0;
    tmp[t] = v;
    __syncthreads();
#pragma unroll
    for (int o = 1; o < 512; o <<= 1) {
        int u = (t >= o) ? tmp[t - o] : 0;
        __syncthreads();
        tmp[t] += u;
        __syncthreads();
    }
    bsums[t] = tmp[t] - v;                           // exclusive
}

// Add block offsets; write final row_start and a working copy into cursor.
__global__ void scan_add_kernel(int* __restrict__ row_start, const int* __restrict__ bsums,
                                int* __restrict__ cursor) {
    int i = blockIdx.x * 256 + threadIdx.x;
    if (i < N_NODES) {
        int v = row_start[i] + bsums[blockIdx.x];
        row_start[i] = v;
        cursor[i] = v;
        if (i == N_NODES - 1) row_start[N_NODES] = N_EDGES;
    }
}

// XCD-binned scatter: bin = blockIdx&7 owns rows [bin*12500, bin*12500+12500).
// All writers of a bin's ~1.6MB CSR region land on one XCD (round-robin dispatch)
// -> edge lines fill completely inside that XCD's L2 -> full-line writebacks.
__global__ __launch_bounds__(256) void scatter_binned_kernel(
    const int* __restrict__ row, const int* __restrict__ col,
    const float* __restrict__ vals, int* __restrict__ cursor,
    uint2* __restrict__ edges) {
    const int bin = blockIdx.x & (N_BINS - 1);
    const int chunk = blockIdx.x >> 3;
    const int lo = bin * BIN_ROWS;
    const int e0 = chunk * SC_CHUNK_EDGES + threadIdx.x;
#pragma unroll 1
    for (int e = e0; e < (chunk + 1) * SC_CHUNK_EDGES; e += 256) {
        int r = row[e];
        if ((unsigned)(r - lo) < (unsigned)BIN_ROWS) {
            int pos = atomicAdd(&cursor[r], 1);
            edges[pos] = make_uint2((unsigned)col[e], __float_as_uint(vals[e]));
        }
    }
}

// ---------- Kernel 3: CSR SpMM, one wave per row, fused bias+ReLU, write-once ----------
__global__ __launch_bounds__(256) void spmm_csr_kernel(
    const unsigned short* __restrict__ preb, const int* __restrict__ row_start,
    const uint2* __restrict__ edges, const float* __restrict__ bias,
    float* __restrict__ out) {
    const int lane = threadIdx.x & 63;
    const int r = blockIdx.x * 4 + (threadIdx.x >> 6);
    const int s = row_start[r];
    const int t = row_start[r + 1];
    float a0 = 0.f, a1 = 0.f;
    int e = s;
    // 4x unrolled gather: independent loads pipeline under the FMA chain.
    for (; e + 4 <= t; e += 4) {
        uint2 cv0 = edges[e + 0];
        uint2 cv1 = edges[e + 1];
        uint2 cv2 = edges[e + 2];
        uint2 cv3 = edges[e + 3];
        unsigned g0 = *reinterpret_cast<const unsigned*>(preb + (size_t)cv0.x * F_OUT + lane * 2);
        unsigned g1 = *reinterpret_cast<const unsigned*>(preb + (size_t)cv1.x * F_OUT + lane * 2);
        unsigned g2 = *reinterpret_cast<const unsigned*>(preb + (size_t)cv2.x * F_OUT + lane * 2);
        unsigned g3 = *reinterpret_cast<const unsigned*>(preb + (size_t)cv3.x * F_OUT + lane * 2);
        float v0 = __uint_as_float(cv0.y), v1 = __uint_as_float(cv1.y);
        float v2 = __uint_as_float(cv2.y), v3 = __uint_as_float(cv3.y);
        a0 += v0 * __uint_as_float(g0 << 16);
        a1 += v0 * __uint_as_float(g0 & 0xFFFF0000u);
        a0 += v1 * __uint_as_float(g1 << 16);
        a1 += v1 * __uint_as_float(g1 & 0xFFFF0000u);
        a0 += v2 * __uint_as_float(g2 << 16);
        a1 += v2 * __uint_as_float(g2 & 0xFFFF0000u);
        a0 += v3 * __uint_as_float(g3 << 16);
        a1 += v3 * __uint_as_float(g3 & 0xFFFF0000u);
    }
    for (; e < t; ++e) {
        uint2 cv = edges[e];
        float v = __uint_as_float(cv.y);
        unsigned g = *reinterpret_cast<const unsigned*>(preb + (size_t)cv.x * F_OUT + lane * 2);
        a0 += v * __uint_as_float(g << 16);
        a1 += v * __uint_as_float(g & 0xFFFF0000u);
    }
    float2 bb = *reinterpret_cast<const float2*>(bias + lane * 2);
    float2 o;
    o.x = fmaxf(a0 + bb.x, 0.f);
    o.y = fmaxf(a1 + bb.y, 0.f);
    *reinterpret_cast<float2*>(out + (size_t)r * F_OUT + lane * 2) = o;
}

extern "C" void kernel_launch(void* const* d_in, const int* in_sizes, int n_in,
                              void* d_out, int out_size, void* d_ws, size_t ws_size,
                              hipStream_t stream) {
    const float* x    = (const float*)d_in[0];
    const float* W    = (const float*)d_in[1];
    const float* b    = (const float*)d_in[2];
    const float* vals = (const float*)d_in[3];
    const int*   row  = (const int*)d_in[4];
    const int*   col  = (const int*)d_in[5];
    float* out = (float*)d_out;

    // Workspace layout (16B-aligned offsets), total ~39.3 MB:
    char* ws = (char*)d_ws;
    unsigned short* preb  = (unsigned short*)(ws);                    // 25,600,000 B
    unsigned short* Wsw   = (unsigned short*)(ws + 25600000);         //     65,536 B
    int*            row_start = (int*)(ws + 25665536);                //    400,016 B (100001 ints)
    int*            cursor    = (int*)(ws + 26065552);                //    400,000 B (deg, then cursors)
    int*            bsums     = (int*)(ws + 26465552);                //      4,096 B
    uint2*          edges     = (uint2*)(ws + 26469648);              // 12,800,000 B

    // deg accumulates in `cursor` first; zero it each call.
    hipMemsetAsync(cursor, 0, N_NODES * sizeof(int), stream);

    wprep_kernel<<<128, 256, 0, stream>>>(W, Wsw);
    gemm_kernel<<<(N_NODES + 63) / 64, 256, 0, stream>>>(x, Wsw, preb);

    hist_kernel<<<(N_EDGES + 255) / 256, 256, 0, stream>>>(row, cursor);
    scan_block_kernel<<<SCAN_BLOCKS, 256, 0, stream>>>(cursor, row_start, bsums);
    scan_bsums_kernel<<<1, 512, 0, stream>>>(bsums);
    scan_add_kernel<<<SCAN_BLOCKS, 256, 0, stream>>>(row_start, bsums, cursor);
    scatter_binned_kernel<<<N_BINS * SC_CHUNKS, 256, 0, stream>>>(row, col, vals, cursor, edges);

    spmm_csr_kernel<<<N_NODES / 4, 256, 0, stream>>>(preb, row_start, edges, b, out);
}